// Round 2
// baseline (928.909 us; speedup 1.0000x reference)
//
#include <hip/hip_runtime.h>
#include <hip/hip_bf16.h>

#define LSEQ 768
#define CA 384
#define CP 128
#define NH 16
#define CH 24
#define EPSV 1e-6f

__device__ __forceinline__ float bf16rt(float x) {
    return __bfloat162float(__float2bfloat16(x));
}

// ---------------- K0: rmsnorm(A_I) -> bf16-rounded f32 ----------------
__global__ __launch_bounds__(384) void k0_rms(const float* __restrict__ A,
                                              const float* __restrict__ w,
                                              float* __restrict__ a) {
    int i = blockIdx.x;
    int t = threadIdx.x;
    float x = A[i * CA + t];
    float ss = x * x;
    #pragma unroll
    for (int o = 32; o; o >>= 1) ss += __shfl_xor(ss, o);
    __shared__ float red[6];
    if ((t & 63) == 0) red[t >> 6] = ss;
    __syncthreads();
    float tot = 0.f;
    #pragma unroll
    for (int k = 0; k < 6; ++k) tot += red[k];
    float rs = rsqrtf(tot / (float)CA + EPSV);
    a[i * CA + t] = bf16rt(x * rs * w[t]);
}

// ---------------- K1: fused Q,K,V,G projections (grid.y = matrix) -----
// rows-per-block = 8; thread t = output column (h*24+d)
__global__ __launch_bounds__(384) void k1_proj4(const float* __restrict__ a,
                                                const float* __restrict__ Wq,
                                                const float* __restrict__ bq,
                                                const float* __restrict__ Wk,
                                                const float* __restrict__ Wv,
                                                const float* __restrict__ Wg,
                                                float* __restrict__ Qo,
                                                float* __restrict__ Ko,
                                                float* __restrict__ Vo,
                                                float* __restrict__ Go) {
    __shared__ float aL[8][CA];
    int t = threadIdx.x;
    int r0 = blockIdx.x * 8;
    int mat = blockIdx.y;
    const float* W = (mat == 0) ? Wq : (mat == 1) ? Wk : (mat == 2) ? Wv : Wg;
    float* O = (mat == 0) ? Qo : (mat == 1) ? Ko : (mat == 2) ? Vo : Go;

    const float4* src = (const float4*)(a + (size_t)r0 * CA);
    float4* dst = (float4*)&aL[0][0];
    for (int idx = t; idx < 8 * CA / 4; idx += 384) dst[idx] = src[idx];
    __syncthreads();

    float acc[8];
    float bv = (mat == 0) ? bq[t] : 0.f;
    #pragma unroll
    for (int r = 0; r < 8; ++r) acc[r] = bv;

    for (int c = 0; c < CA; c += 4) {
        float w0 = W[(size_t)(c + 0) * CA + t];
        float w1 = W[(size_t)(c + 1) * CA + t];
        float w2 = W[(size_t)(c + 2) * CA + t];
        float w3 = W[(size_t)(c + 3) * CA + t];
        #pragma unroll
        for (int r = 0; r < 8; ++r) {
            float4 av = *(const float4*)&aL[r][c];
            acc[r] += av.x * w0 + av.y * w1 + av.z * w2 + av.w * w3;
        }
    }
    #pragma unroll
    for (int r = 0; r < 8; ++r) {
        float v = acc[r];
        if (mat == 3) v = 1.f / (1.f + expf(-v));
        O[(size_t)(r0 + r) * CA + t] = v;
    }
}

// ---------------- single GEMM: out = X @ Wa -------------------
__global__ __launch_bounds__(384) void k_gemm1(const float* __restrict__ a,
                                               const float* __restrict__ W,
                                               float* __restrict__ O) {
    __shared__ float aL[8][CA];
    int t = threadIdx.x;
    int r0 = blockIdx.x * 8;
    const float4* src = (const float4*)(a + (size_t)r0 * CA);
    float4* dst = (float4*)&aL[0][0];
    for (int idx = t; idx < 8 * CA / 4; idx += 384) dst[idx] = src[idx];
    __syncthreads();
    float acc[8];
    #pragma unroll
    for (int r = 0; r < 8; ++r) acc[r] = 0.f;
    for (int c = 0; c < CA; c += 4) {
        float w0 = W[(size_t)(c + 0) * CA + t];
        float w1 = W[(size_t)(c + 1) * CA + t];
        float w2 = W[(size_t)(c + 2) * CA + t];
        float w3 = W[(size_t)(c + 3) * CA + t];
        #pragma unroll
        for (int r = 0; r < 8; ++r) {
            float4 av = *(const float4*)&aL[r][c];
            acc[r] += av.x * w0 + av.y * w1 + av.z * w2 + av.w * w3;
        }
    }
    #pragma unroll
    for (int r = 0; r < 8; ++r) O[(size_t)(r0 + r) * CA + t] = acc[r];
}

// ---------------- K2: scores[i][j][h] = scale*Q·K + rmsnorm(Z)·Wb + beta
// one wave per (i,j) pair; 4 waves/block; 4 pair-iterations per block
#define PAIRS_PER_BLOCK 16
__global__ __launch_bounds__(256) void k2_scores(const float* __restrict__ Z,
                                                 const float* __restrict__ Beta,
                                                 const float* __restrict__ ln0,
                                                 const float* __restrict__ Wb,
                                                 const float* __restrict__ Q,
                                                 const float* __restrict__ K,
                                                 float* __restrict__ S) {
    __shared__ float zl[4][CP];
    int t = threadIdx.x;
    int w = t >> 6, l = t & 63;
    int h = l & 15, qq = l >> 4;
    const float scale = 1.f / sqrtf((float)CH);

    // preload this lane's slice of Wb (folded with ln0 weight) into registers
    float4 wbv[8];
    #pragma unroll
    for (int m = 0; m < 8; ++m) {
        int k = ((4 * m) + 8 * qq) & 31;
        int p = qq * 32 + k;
        wbv[m] = make_float4(Wb[(size_t)(p + 0) * NH + h] * ln0[p + 0],
                             Wb[(size_t)(p + 1) * NH + h] * ln0[p + 1],
                             Wb[(size_t)(p + 2) * NH + h] * ln0[p + 2],
                             Wb[(size_t)(p + 3) * NH + h] * ln0[p + 3]);
    }

    for (int it = 0; it < PAIRS_PER_BLOCK / 4; ++it) {
        int pair = blockIdx.x * PAIRS_PER_BLOCK + it * 4 + w;
        int i = pair / LSEQ;
        int j = pair - i * LSEQ;

        float2 z = *(const float2*)&Z[(size_t)pair * CP + 2 * l];
        float ss = z.x * z.x + z.y * z.y;
        #pragma unroll
        for (int o = 32; o; o >>= 1) ss += __shfl_xor(ss, o);
        float rs = rsqrtf(ss * (1.0f / CP) + EPSV);
        zl[w][2 * l + 0] = z.x * rs;
        zl[w][2 * l + 1] = z.y * rs;
        __syncthreads();

        // bias projection: lane covers p in [qq*32, qq*32+32), bank-rotated
        float acc = 0.f;
        #pragma unroll
        for (int m = 0; m < 8; ++m) {
            int k = ((4 * m) + 8 * qq) & 31;
            int p = qq * 32 + k;
            float4 zv = *(const float4*)&zl[w][p];
            acc += zv.x * wbv[m].x + zv.y * wbv[m].y + zv.z * wbv[m].z + zv.w * wbv[m].w;
        }
        acc += __shfl_xor(acc, 16);
        acc += __shfl_xor(acc, 32);

        // QK^T: lane covers c in [qq*6, qq*6+6)
        float qk = 0.f;
        const float* qrow = Q + ((size_t)i * NH + h) * CH;
        const float* krow = K + ((size_t)j * NH + h) * CH;
        #pragma unroll
        for (int c = 0; c < 6; ++c) qk += qrow[qq * 6 + c] * krow[qq * 6 + c];
        qk += __shfl_xor(qk, 16);
        qk += __shfl_xor(qk, 32);

        float sval = qk * scale + acc + Beta[pair];
        if (qq == 0) S[(size_t)pair * NH + h] = sval;
        __syncthreads();
    }
}

// ---------------- K3: softmax over j + A@V + gate ----------------------
// one block per 2 query rows; scores staged in LDS
__global__ __launch_bounds__(384) void k3_softmax_av(const float* __restrict__ S,
                                                     const float* __restrict__ V,
                                                     const float* __restrict__ G,
                                                     float* __restrict__ X) {
    __shared__ float A0[LSEQ * NH];
    __shared__ float A1[LSEQ * NH];
    __shared__ float red[2][NH][12];
    __shared__ float m_s[2][NH];
    __shared__ float rsum[2][NH];
    int t = threadIdx.x;
    int i0 = blockIdx.x * 2;

    const float4* s0 = (const float4*)(S + (size_t)i0 * LSEQ * NH);
    const float4* s1 = (const float4*)(S + (size_t)(i0 + 1) * LSEQ * NH);
    float4* d0 = (float4*)A0;
    float4* d1 = (float4*)A1;
    for (int idx = t; idx < LSEQ * NH / 4; idx += 384) {
        d0[idx] = s0[idx];
        d1[idx] = s1[idx];
    }
    __syncthreads();

    // max over j: t -> (r = t/192, h = t&15, seg = (t%192)>>4, 12 segs x 64 j)
    int r = t / 192, rem = t % 192, h = rem & 15, seg = rem >> 4;
    float* Abuf = r ? A1 : A0;
    float mx = -1e30f;
    for (int j = seg * 64; j < seg * 64 + 64; ++j) mx = fmaxf(mx, Abuf[j * NH + h]);
    red[r][h][seg] = mx;
    __syncthreads();
    if (t < 32) {
        int rr = t >> 4, hh = t & 15;
        float m = -1e30f;
        #pragma unroll
        for (int k = 0; k < 12; ++k) m = fmaxf(m, red[rr][hh][k]);
        m_s[rr][hh] = m;
    }
    __syncthreads();
    float m = m_s[r][h];
    float ps = 0.f;
    for (int j = seg * 64; j < seg * 64 + 64; ++j) {
        float e = expf(Abuf[j * NH + h] - m);
        Abuf[j * NH + h] = e;
        ps += e;
    }
    red[r][h][seg] = ps;
    __syncthreads();
    if (t < 32) {
        int rr = t >> 4, hh = t & 15;
        float s = 0.f;
        #pragma unroll
        for (int k = 0; k < 12; ++k) s += red[rr][hh][k];
        rsum[rr][hh] = 1.f / s;
    }
    __syncthreads();

    // AV: thread t -> (h2 = t/24, c = t%24), both rows share each V read
    int h2 = t / CH, c = t - h2 * CH;
    float acc0 = 0.f, acc1 = 0.f;
    for (int j = 0; j < LSEQ; ++j) {
        float v = V[((size_t)j * NH + h2) * CH + c];
        acc0 += A0[j * NH + h2] * v;
        acc1 += A1[j * NH + h2] * v;
    }
    int col = h2 * CH + c;
    X[(size_t)i0 * CA + col]       = acc0 * rsum[0][h2] * G[(size_t)i0 * CA + col];
    X[(size_t)(i0 + 1) * CA + col] = acc1 * rsum[1][h2] * G[(size_t)(i0 + 1) * CA + col];
}

extern "C" void kernel_launch(void* const* d_in, const int* in_sizes, int n_in,
                              void* d_out, int out_size, void* d_ws, size_t ws_size,
                              hipStream_t stream) {
    const float* A_I  = (const float*)d_in[0];
    const float* Z    = (const float*)d_in[1];
    const float* Beta = (const float*)d_in[2];
    const float* ln1  = (const float*)d_in[3];
    const float* ln0  = (const float*)d_in[4];
    const float* Wq   = (const float*)d_in[5];
    const float* bq   = (const float*)d_in[6];
    const float* Wk   = (const float*)d_in[7];
    const float* Wv   = (const float*)d_in[8];
    const float* Wb   = (const float*)d_in[9];
    const float* Wg   = (const float*)d_in[10];
    const float* Wa   = (const float*)d_in[11];
    float* out = (float*)d_out;

    float* ws = (float*)d_ws;
    float* a  = ws;                 // 294912 floats region start
    float* Qw = ws + 294912;
    float* Kw = ws + 589824;
    float* Vw = ws + 884736;
    float* Gw = ws + 1179648;
    float* Xw = ws + 1474560;
    float* S  = ws + 1769472;       // 9437184 floats (37.7 MB)

    k0_rms<<<LSEQ, 384, 0, stream>>>(A_I, ln1, a);
    k1_proj4<<<dim3(96, 4), 384, 0, stream>>>(a, Wq, bq, Wk, Wv, Wg, Qw, Kw, Vw, Gw);
    k2_scores<<<(LSEQ * LSEQ) / PAIRS_PER_BLOCK, 256, 0, stream>>>(Z, Beta, ln0, Wb, Qw, Kw, S);
    k3_softmax_av<<<LSEQ / 2, 384, 0, stream>>>(S, Vw, Gw, Xw);
    k_gemm1<<<96, 384, 0, stream>>>(Xw, Wa, out);
}

// Round 7
// 710.819 us; speedup vs baseline: 1.3068x; 1.3068x over previous
//
#include <hip/hip_runtime.h>
#include <hip/hip_bf16.h>

#define LSEQ 768
#define CA 384
#define CP 128
#define NH 16
#define CH 24
#define EPSV 1e-6f
#define SLD 17   // padded LDS row stride (conflict-free: 17 odd)

__device__ __forceinline__ float bf16rt(float x) {
    return __bfloat162float(__float2bfloat16(x));
}

// ---------------- K0: rmsnorm(A_I) -> bf16-rounded f32 ----------------
__global__ __launch_bounds__(384) void k0_rms(const float* __restrict__ A,
                                              const float* __restrict__ w,
                                              float* __restrict__ a) {
    int i = blockIdx.x;
    int t = threadIdx.x;
    float x = A[i * CA + t];
    float ss = x * x;
    #pragma unroll
    for (int o = 32; o; o >>= 1) ss += __shfl_xor(ss, o);
    __shared__ float red[6];
    if ((t & 63) == 0) red[t >> 6] = ss;
    __syncthreads();
    float tot = 0.f;
    #pragma unroll
    for (int k = 0; k < 6; ++k) tot += red[k];
    float rs = rsqrtf(tot / (float)CA + EPSV);
    a[i * CA + t] = bf16rt(x * rs * w[t]);
}

// ---------------- K1: fused Q,K,V,G projections (grid.y = matrix) -----
__global__ __launch_bounds__(384) void k1_proj4(const float* __restrict__ a,
                                                const float* __restrict__ Wq,
                                                const float* __restrict__ bq,
                                                const float* __restrict__ Wk,
                                                const float* __restrict__ Wv,
                                                const float* __restrict__ Wg,
                                                float* __restrict__ Qo,
                                                float* __restrict__ Ko,
                                                float* __restrict__ Vo,
                                                float* __restrict__ Go) {
    __shared__ float aL[8][CA];
    int t = threadIdx.x;
    int r0 = blockIdx.x * 8;
    int mat = blockIdx.y;
    const float* W = (mat == 0) ? Wq : (mat == 1) ? Wk : (mat == 2) ? Wv : Wg;
    float* O = (mat == 0) ? Qo : (mat == 1) ? Ko : (mat == 2) ? Vo : Go;

    const float4* src = (const float4*)(a + (size_t)r0 * CA);
    float4* dst = (float4*)&aL[0][0];
    for (int idx = t; idx < 8 * CA / 4; idx += 384) dst[idx] = src[idx];
    __syncthreads();

    float acc[8];
    float bv = (mat == 0) ? bq[t] : 0.f;
    #pragma unroll
    for (int r = 0; r < 8; ++r) acc[r] = bv;

    for (int c = 0; c < CA; c += 4) {
        float w0 = W[(size_t)(c + 0) * CA + t];
        float w1 = W[(size_t)(c + 1) * CA + t];
        float w2 = W[(size_t)(c + 2) * CA + t];
        float w3 = W[(size_t)(c + 3) * CA + t];
        #pragma unroll
        for (int r = 0; r < 8; ++r) {
            float4 av = *(const float4*)&aL[r][c];
            acc[r] += av.x * w0 + av.y * w1 + av.z * w2 + av.w * w3;
        }
    }
    #pragma unroll
    for (int r = 0; r < 8; ++r) {
        float v = acc[r];
        if (mat == 3) v = 1.f / (1.f + expf(-v));
        O[(size_t)(r0 + r) * CA + t] = v;
    }
}

// ---------------- final GEMM: out = X @ Wa -----------------------------
__global__ __launch_bounds__(384) void k_gemm1(const float* __restrict__ a,
                                               const float* __restrict__ W,
                                               float* __restrict__ O) {
    __shared__ float aL[8][CA];
    int t = threadIdx.x;
    int r0 = blockIdx.x * 8;
    const float4* src = (const float4*)(a + (size_t)r0 * CA);
    float4* dst = (float4*)&aL[0][0];
    for (int idx = t; idx < 8 * CA / 4; idx += 384) dst[idx] = src[idx];
    __syncthreads();
    float acc[8];
    #pragma unroll
    for (int r = 0; r < 8; ++r) acc[r] = 0.f;
    for (int c = 0; c < CA; c += 4) {
        float w0 = W[(size_t)(c + 0) * CA + t];
        float w1 = W[(size_t)(c + 1) * CA + t];
        float w2 = W[(size_t)(c + 2) * CA + t];
        float w3 = W[(size_t)(c + 3) * CA + t];
        #pragma unroll
        for (int r = 0; r < 8; ++r) {
            float4 av = *(const float4*)&aL[r][c];
            acc[r] += av.x * w0 + av.y * w1 + av.z * w2 + av.w * w3;
        }
    }
    #pragma unroll
    for (int r = 0; r < 8; ++r) O[(size_t)(r0 + r) * CA + t] = acc[r];
}

// ---------------- K_attn: fused bias-proj + QK + softmax + AV + gate ---
// One block per query row i. 256 threads = 8 groups of 32 lanes.
// Group g handles pairs j = jt*8 + g. Lane l covers p in [4l, 4l+4).
// After tree reduce, lane l owns head h=(l>>1)&15 (dup across l&1).
__global__ __launch_bounds__(256, 3) void k_attn(const float* __restrict__ Z,
                                                 const float* __restrict__ Beta,
                                                 const float* __restrict__ ln0,
                                                 const float* __restrict__ Wb,
                                                 const float* __restrict__ Q,
                                                 const float* __restrict__ K,
                                                 const float* __restrict__ V,
                                                 const float* __restrict__ G,
                                                 float* __restrict__ X) {
    __shared__ float S_lds[LSEQ * SLD];
    __shared__ float rsums[NH];
    const int t = threadIdx.x;
    const int i = blockIdx.x;
    const int grp = t >> 5;
    const int l = t & 31;
    const int h = (l >> 1) & 15;
    const int b0 = l & 1;
    const float scale = 0.20412414523193154f;  // 1/sqrt(24)

    // ---- persistent per-lane weights: w[k][m] = Wb[4l+k][m] * ln0[4l+k]
    float w[4][16];
    {
        const float4 lnv = *(const float4*)&ln0[4 * l];
        const float lw[4] = {lnv.x, lnv.y, lnv.z, lnv.w};
        #pragma unroll
        for (int k = 0; k < 4; ++k) {
            const float4* wr = (const float4*)&Wb[(size_t)(4 * l + k) * NH];
            float4 a0 = wr[0], a1 = wr[1], a2 = wr[2], a3 = wr[3];
            w[k][0] = a0.x * lw[k];  w[k][1] = a0.y * lw[k];
            w[k][2] = a0.z * lw[k];  w[k][3] = a0.w * lw[k];
            w[k][4] = a1.x * lw[k];  w[k][5] = a1.y * lw[k];
            w[k][6] = a1.z * lw[k];  w[k][7] = a1.w * lw[k];
            w[k][8] = a2.x * lw[k];  w[k][9] = a2.y * lw[k];
            w[k][10] = a2.z * lw[k]; w[k][11] = a2.w * lw[k];
            w[k][12] = a3.x * lw[k]; w[k][13] = a3.y * lw[k];
            w[k][14] = a3.z * lw[k]; w[k][15] = a3.w * lw[k];
        }
    }
    // ---- persistent Q fragment: 12 floats of Q[i][h][b0*12 ..]
    float q[12];
    {
        const float4* qp = (const float4*)&Q[(size_t)i * CA + h * CH + b0 * 12];
        float4 q0 = qp[0], q1 = qp[1], q2 = qp[2];
        q[0] = q0.x; q[1] = q0.y; q[2] = q0.z; q[3] = q0.w;
        q[4] = q1.x; q[5] = q1.y; q[6] = q1.z; q[7] = q1.w;
        q[8] = q2.x; q[9] = q2.y; q[10] = q2.z; q[11] = q2.w;
    }

    // ---- phase 1: stream Z row-panel, write scores to LDS -------------
    int j = grp;
    float4 z = *(const float4*)&Z[((size_t)i * LSEQ + j) * CP + 4 * l];

    for (int jt = 0; jt < LSEQ / 8; ++jt) {
        const int jn = (jt == LSEQ / 8 - 1) ? j : (j + 8);
        // prefetch next z (branchless clamp; last iter re-reads same row)
        float4 zn = *(const float4*)&Z[((size_t)i * LSEQ + jn) * CP + 4 * l];
        // issue K + beta early (consumed after the tree reduce)
        const float4* kp = (const float4*)&K[(size_t)j * CA + h * CH + b0 * 12];
        float4 k0v = kp[0], k1v = kp[1], k2v = kp[2];
        float beta = Beta[(size_t)i * LSEQ + j];

        float ssq = z.x * z.x + z.y * z.y + z.z * z.z + z.w * z.w;
        float acc[16];
        #pragma unroll
        for (int m = 0; m < 16; ++m)
            acc[m] = z.x * w[0][m] + z.y * w[1][m] + z.z * w[2][m] + z.w * w[3][m];

        // tree reduce over lanes: levels d=16,8,4,2 halve the acc set
        const bool bit4 = (l & 16) != 0;
        #pragma unroll
        for (int k = 0; k < 8; ++k) {
            float send = bit4 ? acc[k] : acc[k + 8];
            float recv = __shfl_xor(send, 16);
            acc[k] = (bit4 ? acc[k + 8] : acc[k]) + recv;
        }
        const bool bit3 = (l & 8) != 0;
        #pragma unroll
        for (int k = 0; k < 4; ++k) {
            float send = bit3 ? acc[k] : acc[k + 4];
            float recv = __shfl_xor(send, 8);
            acc[k] = (bit3 ? acc[k + 4] : acc[k]) + recv;
        }
        const bool bit2 = (l & 4) != 0;
        #pragma unroll
        for (int k = 0; k < 2; ++k) {
            float send = bit2 ? acc[k] : acc[k + 2];
            float recv = __shfl_xor(send, 4);
            acc[k] = (bit2 ? acc[k + 2] : acc[k]) + recv;
        }
        const bool bit1 = (l & 2) != 0;
        {
            float send = bit1 ? acc[0] : acc[1];
            float recv = __shfl_xor(send, 2);
            acc[0] = (bit1 ? acc[1] : acc[0]) + recv;
        }
        acc[0] += __shfl_xor(acc[0], 1);  // merge complementary p-halves

        // ss butterfly (full 32-lane sum)
        ssq += __shfl_xor(ssq, 1);
        ssq += __shfl_xor(ssq, 2);
        ssq += __shfl_xor(ssq, 4);
        ssq += __shfl_xor(ssq, 8);
        ssq += __shfl_xor(ssq, 16);
        float rs = rsqrtf(ssq * (1.0f / CP) + EPSV);

        // qk: 12-dim partial dot, merged across lane pair
        float qk = q[0] * k0v.x + q[1] * k0v.y + q[2] * k0v.z + q[3] * k0v.w +
                   q[4] * k1v.x + q[5] * k1v.y + q[6] * k1v.z + q[7] * k1v.w +
                   q[8] * k2v.x + q[9] * k2v.y + q[10] * k2v.z + q[11] * k2v.w;
        qk += __shfl_xor(qk, 1);

        float sval = qk * scale + acc[0] * rs + beta;
        if (b0 == 0) S_lds[j * SLD + h] = sval;
        j = jn;
        z = zn;
    }
    __syncthreads();

    // ---- phase 2a: softmax over j (16 lanes per head) -----------------
    {
        const int sh_ = t >> 4;  // head
        const int sl_ = t & 15;  // lane within head group
        float mx = -1e30f;
        #pragma unroll 4
        for (int k = 0; k < LSEQ / 16; ++k)
            mx = fmaxf(mx, S_lds[(sl_ + 16 * k) * SLD + sh_]);
        mx = fmaxf(mx, __shfl_xor(mx, 1));
        mx = fmaxf(mx, __shfl_xor(mx, 2));
        mx = fmaxf(mx, __shfl_xor(mx, 4));
        mx = fmaxf(mx, __shfl_xor(mx, 8));
        float sum = 0.f;
        #pragma unroll 4
        for (int k = 0; k < LSEQ / 16; ++k) {
            int idx = (sl_ + 16 * k) * SLD + sh_;
            float e = __expf(S_lds[idx] - mx);
            S_lds[idx] = e;
            sum += e;
        }
        sum += __shfl_xor(sum, 1);
        sum += __shfl_xor(sum, 2);
        sum += __shfl_xor(sum, 4);
        sum += __shfl_xor(sum, 8);
        if (sl_ == 0) rsums[sh_] = 1.0f / sum;
    }
    __syncthreads();

    // ---- phase 2b: AV + gate ------------------------------------------
    {
        int col = t;
        int h2 = col / CH;
        float acc = 0.f;
        #pragma unroll 8
        for (int jj = 0; jj < LSEQ; ++jj)
            acc += S_lds[jj * SLD + h2] * V[(size_t)jj * CA + col];
        X[(size_t)i * CA + col] = acc * rsums[h2] * G[(size_t)i * CA + col];
    }
    if (t < CA - 256) {
        int col = t + 256;
        int h2 = col / CH;
        float acc = 0.f;
        #pragma unroll 8
        for (int jj = 0; jj < LSEQ; ++jj)
            acc += S_lds[jj * SLD + h2] * V[(size_t)jj * CA + col];
        X[(size_t)i * CA + col] = acc * rsums[h2] * G[(size_t)i * CA + col];
    }
}

extern "C" void kernel_launch(void* const* d_in, const int* in_sizes, int n_in,
                              void* d_out, int out_size, void* d_ws, size_t ws_size,
                              hipStream_t stream) {
    const float* A_I  = (const float*)d_in[0];
    const float* Z    = (const float*)d_in[1];
    const float* Beta = (const float*)d_in[2];
    const float* ln1  = (const float*)d_in[3];
    const float* ln0  = (const float*)d_in[4];
    const float* Wq   = (const float*)d_in[5];
    const float* bq   = (const float*)d_in[6];
    const float* Wk   = (const float*)d_in[7];
    const float* Wv   = (const float*)d_in[8];
    const float* Wb   = (const float*)d_in[9];
    const float* Wg   = (const float*)d_in[10];
    const float* Wa   = (const float*)d_in[11];
    float* out = (float*)d_out;

    float* ws = (float*)d_ws;
    float* a  = ws;
    float* Qw = ws + 294912;
    float* Kw = ws + 589824;
    float* Vw = ws + 884736;
    float* Gw = ws + 1179648;
    float* Xw = ws + 1474560;

    k0_rms<<<LSEQ, 384, 0, stream>>>(A_I, ln1, a);
    k1_proj4<<<dim3(96, 4), 384, 0, stream>>>(a, Wq, bq, Wk, Wv, Wg, Qw, Kw, Vw, Gw);
    k_attn<<<LSEQ, 256, 0, stream>>>(Z, Beta, ln0, Wb, Qw, Kw, Vw, Gw, Xw);
    k_gemm1<<<96, 384, 0, stream>>>(Xw, Wa, out);
}